// Round 2
// baseline (519.428 us; speedup 1.0000x reference)
//
#include <hip/hip_runtime.h>
#include <hip/hip_bf16.h>

// LiftedStructureLoss on MI355X (gfx950)
// N=8192, D=128 fp32 embeddings; int labels; scalar fp32 out.
//
// ws layout:
//   [0]        double total
//   [8]        unsigned npos
//   [64]       float sum_exp[N]          (zeroed each launch)
//   [64+4N]    float sq[N]
//   [64+8N]    bf16  ebf[N*128]          (row-major, 256B rows)

typedef __attribute__((ext_vector_type(8))) short bf16x8;
typedef __attribute__((ext_vector_type(4))) float f32x4;

__device__ __forceinline__ unsigned short f2bf(float f) {
    unsigned u = __float_as_uint(f);
    u += 0x7fffu + ((u >> 16) & 1u);   // round-to-nearest-even
    return (unsigned short)(u >> 16);
}

// One wave per row: row sum-of-squares (fp32) + bf16 conversion.
__global__ void prep_kernel(const float* __restrict__ e, float* __restrict__ sq,
                            unsigned* __restrict__ ebf, int N) {
    int row = blockIdx.x;
    int lane = threadIdx.x;                       // 64 lanes, 2 cols each
    float2 v = ((const float2*)(e + (size_t)row * 128))[lane];
    float s = v.x * v.x + v.y * v.y;
    #pragma unroll
    for (int off = 1; off < 64; off <<= 1) s += __shfl_xor(s, off, 64);
    if (lane == 0) sq[row] = s;
    unsigned bits = (unsigned)f2bf(v.x) | ((unsigned)f2bf(v.y) << 16);
    ebf[(size_t)row * 64 + lane] = bits;
}

// PASS 1: accumulate sum_exp rows. PASS 2: accumulate loss + n_pos.
// 128x128 tile per block, 4 waves (2x2 of 64x64), K=128 in one shot.
template<int PASS>
__global__ __launch_bounds__(256) void pass_kernel(
    const unsigned short* __restrict__ ebf,
    const float* __restrict__ sq,
    const int* __restrict__ labels,
    float* __restrict__ sum_exp,
    double* __restrict__ total,
    unsigned* __restrict__ npos,
    int N)
{
    __shared__ __align__(16) char a_tile[128 * 256];  // [row][256B], XOR-swizzled
    __shared__ __align__(16) char b_tile[128 * 256];

    const int tid = threadIdx.x;
    const int lane = tid & 63, wid = tid >> 6;
    const int brow = blockIdx.y * 128, bcol = blockIdx.x * 128;

    // ---- stage both tiles (bf16 rows of E), 16B chunks, swizzled ----
    #pragma unroll
    for (int i = 0; i < 8; ++i) {
        int chunk = tid + i * 256;          // 2048 chunks of 16B per tile
        int r  = chunk >> 4;                // tile row
        int cb = (chunk & 15) * 16;         // byte col
        int sc = cb ^ ((r & 7) << 4);       // G4 XOR swizzle
        uint4 va = *(const uint4*)((const char*)ebf + ((size_t)(brow + r) << 8) + cb);
        *(uint4*)(a_tile + r * 256 + sc) = va;
        uint4 vb = *(const uint4*)((const char*)ebf + ((size_t)(bcol + r) << 8) + cb);
        *(uint4*)(b_tile + r * 256 + sc) = vb;
    }
    __syncthreads();

    const int wm = (wid >> 1) * 64, wn = (wid & 1) * 64;
    const int lhi = lane >> 4, llo = lane & 15;

    f32x4 acc[4][4];
    #pragma unroll
    for (int m = 0; m < 4; ++m)
        #pragma unroll
        for (int n = 0; n < 4; ++n)
            acc[m][n] = (f32x4){0.f, 0.f, 0.f, 0.f};

    // ---- MFMA: G = A . B^T  (B tile stored row-major like A; B-frag wants
    //      8 consecutive k for col=llo, which is contiguous in our layout) ----
    #pragma unroll
    for (int ks = 0; ks < 4; ++ks) {
        const int cb = ks * 64 + lhi * 16;  // byte col of this lane's 8 bf16
        bf16x8 af[4], bfr[4];
        #pragma unroll
        for (int m = 0; m < 4; ++m) {
            int r = wm + m * 16 + llo;
            af[m] = *(const bf16x8*)(a_tile + r * 256 + (cb ^ ((r & 7) << 4)));
        }
        #pragma unroll
        for (int n = 0; n < 4; ++n) {
            int r = wn + n * 16 + llo;
            bfr[n] = *(const bf16x8*)(b_tile + r * 256 + (cb ^ ((r & 7) << 4)));
        }
        #pragma unroll
        for (int m = 0; m < 4; ++m)
            #pragma unroll
            for (int n = 0; n < 4; ++n)
                acc[m][n] = __builtin_amdgcn_mfma_f32_16x16x32_bf16(af[m], bfr[n], acc[m][n], 0, 0, 0);
    }

    // ---- epilogue preloads ----
    // C/D layout (verified, guide §3): col = lane&15, row = (lane>>4)*4 + reg
    const int rowbase = brow + wm;
    float sqr[4][4]; int labr[4][4]; float ser[4][4];
    #pragma unroll
    for (int m = 0; m < 4; ++m)
        #pragma unroll
        for (int r = 0; r < 4; ++r) {
            int row = rowbase + m * 16 + lhi * 4 + r;
            sqr[m][r] = sq[row];
            labr[m][r] = labels[row];
            if (PASS == 2) ser[m][r] = sum_exp[row];
        }
    float sqc[4]; int labc[4]; float sec[4];
    #pragma unroll
    for (int n = 0; n < 4; ++n) {
        int col = bcol + wn + n * 16 + llo;
        sqc[n] = sq[col];
        labc[n] = labels[col];
        if (PASS == 2) sec[n] = sum_exp[col];
    }

    if (PASS == 1) {
        float wsum[4][4] = {};
        #pragma unroll
        for (int m = 0; m < 4; ++m)
            #pragma unroll
            for (int n = 0; n < 4; ++n)
                #pragma unroll
                for (int r = 0; r < 4; ++r) {
                    float g = acc[m][n][r];
                    float d2 = fmaxf(sqr[m][r] + sqc[n] - 2.f * g, 0.f);
                    float dist = sqrtf(d2);
                    // diagonal auto-excluded: label_i == label_i
                    float w = (labr[m][r] != labc[n]) ? __expf(1.0f - dist) : 0.f;
                    wsum[m][r] += w;
                }
        // row-sum across the 16 llo lanes (cols) of each lane-group
        #pragma unroll
        for (int m = 0; m < 4; ++m)
            #pragma unroll
            for (int r = 0; r < 4; ++r) {
                float s = wsum[m][r];
                #pragma unroll
                for (int off = 1; off < 16; off <<= 1) s += __shfl_xor(s, off, 64);
                wsum[m][r] = s;
            }
        if (llo == 0) {
            #pragma unroll
            for (int m = 0; m < 4; ++m)
                #pragma unroll
                for (int r = 0; r < 4; ++r)
                    unsafeAtomicAdd(&sum_exp[rowbase + m * 16 + lhi * 4 + r], wsum[m][r]);
        }
    } else {
        float lsum = 0.f; unsigned cnt = 0;
        #pragma unroll
        for (int m = 0; m < 4; ++m)
            #pragma unroll
            for (int n = 0; n < 4; ++n)
                #pragma unroll
                for (int r = 0; r < 4; ++r) {
                    float g = acc[m][n][r];
                    float d2 = fmaxf(sqr[m][r] + sqc[n] - 2.f * g, 0.f);
                    float dist = sqrtf(d2);
                    int row = rowbase + m * 16 + lhi * 4 + r;
                    int col = bcol + wn + n * 16 + llo;
                    bool pos = (labr[m][r] == labc[n]) && (row != col);
                    float L = __logf(ser[m][r] + sec[n]) + dist;
                    L = fmaxf(L, 0.f);
                    lsum += pos ? L * L : 0.f;
                    cnt  += pos ? 1u : 0u;
                }
        #pragma unroll
        for (int off = 1; off < 64; off <<= 1) {
            lsum += __shfl_xor(lsum, off, 64);
            cnt  += __shfl_xor(cnt, off, 64);
        }
        if (lane == 0) {
            atomicAdd(total, (double)lsum);
            atomicAdd(npos, cnt);
        }
    }
}

__global__ void finalize_kernel(const double* __restrict__ total,
                                const unsigned* __restrict__ npos,
                                float* __restrict__ out) {
    if (threadIdx.x == 0 && blockIdx.x == 0) {
        unsigned np = *npos; if (np == 0) np = 1;
        out[0] = (float)(*total / (double)np * 0.5);
    }
}

extern "C" void kernel_launch(void* const* d_in, const int* in_sizes, int n_in,
                              void* d_out, int out_size, void* d_ws, size_t ws_size,
                              hipStream_t stream) {
    const float* e = (const float*)d_in[0];
    const int* labels = (const int*)d_in[1];
    const int N = in_sizes[1];                 // 8192
    char* ws = (char*)d_ws;
    double*   total   = (double*)ws;
    unsigned* npos    = (unsigned*)(ws + 8);
    float*    sum_exp = (float*)(ws + 64);
    float*    sq      = (float*)(ws + 64 + 4 * (size_t)N);
    unsigned short* ebf = (unsigned short*)(ws + 64 + 8 * (size_t)N);

    (void)hipMemsetAsync(d_ws, 0, 64 + 4 * (size_t)N, stream);   // total, npos, sum_exp
    prep_kernel<<<N, 64, 0, stream>>>(e, sq, (unsigned*)ebf, N);
    dim3 grid(N / 128, N / 128);
    pass_kernel<1><<<grid, 256, 0, stream>>>(ebf, sq, labels, sum_exp, total, npos, N);
    pass_kernel<2><<<grid, 256, 0, stream>>>(ebf, sq, labels, sum_exp, total, npos, N);
    finalize_kernel<<<1, 64, 0, stream>>>(total, npos, (float*)d_out);
}

// Round 3
// 182.343 us; speedup vs baseline: 2.8486x; 2.8486x over previous
//
#include <hip/hip_runtime.h>
#include <hip/hip_bf16.h>

// LiftedStructureLoss on MI355X (gfx950)
// N=8192, D=128 fp32 embeddings; int labels; scalar fp32 out.
//
// ws layout (floats unless noted):
//   [0]                sq[N]
//   [4N]               sum_exp[N]
//   [8N]               bf16 ebf[N*128]            (2 MB)
//   [8N+2N*128]        partial1[nCb][N]           (nCb = N/128, 2 MB)
//   [... +4]           double partial2[nB]        (nB = (N/128)^2, 32 KB)
//   [...]              unsigned cnt2[nB]

typedef __attribute__((ext_vector_type(8))) short bf16x8;
typedef __attribute__((ext_vector_type(4))) float f32x4;

__device__ __forceinline__ unsigned short f2bf(float f) {
    unsigned u = __float_as_uint(f);
    u += 0x7fffu + ((u >> 16) & 1u);   // round-to-nearest-even
    return (unsigned short)(u >> 16);
}

// One wave per row: row sum-of-squares (fp32) + bf16 conversion.
__global__ void prep_kernel(const float* __restrict__ e, float* __restrict__ sq,
                            unsigned* __restrict__ ebf, int N) {
    int row = blockIdx.x;
    int lane = threadIdx.x;                       // 64 lanes, 2 cols each
    float2 v = ((const float2*)(e + (size_t)row * 128))[lane];
    float s = v.x * v.x + v.y * v.y;
    #pragma unroll
    for (int off = 1; off < 64; off <<= 1) s += __shfl_xor(s, off, 64);
    if (lane == 0) sq[row] = s;
    unsigned bits = (unsigned)f2bf(v.x) | ((unsigned)f2bf(v.y) << 16);
    ebf[(size_t)row * 64 + lane] = bits;
}

// PASS 1: per-block partial row sums of exp(1-d) over negatives -> partial1.
// PASS 2: per-block partial loss + n_pos -> partial2/cnt2.
// 128x128 tile per block, 4 waves (2x2 of 64x64), K=128 in one shot.
template<int PASS>
__global__ __launch_bounds__(256) void pass_kernel(
    const unsigned short* __restrict__ ebf,
    const float* __restrict__ sq,
    const int* __restrict__ labels,
    const float* __restrict__ sum_exp,   // read in PASS 2
    float* __restrict__ partial1,        // [nCb][N], written in PASS 1
    double* __restrict__ partial2,       // [nB], written in PASS 2
    unsigned* __restrict__ cnt2,         // [nB], written in PASS 2
    int N)
{
    __shared__ __align__(16) char a_tile[128 * 256];  // [row][256B], XOR-swizzled
    __shared__ __align__(16) char b_tile[128 * 256];
    __shared__ float rowsum[128];                     // PASS 1 block combine
    __shared__ double bsum[4];                        // PASS 2 block combine
    __shared__ unsigned bcnt[4];

    const int tid = threadIdx.x;
    const int lane = tid & 63, wid = tid >> 6;
    const int brow = blockIdx.y * 128, bcol = blockIdx.x * 128;

    if (PASS == 1 && tid < 128) rowsum[tid] = 0.f;

    // ---- stage both tiles (bf16 rows of E), 16B chunks, swizzled ----
    #pragma unroll
    for (int i = 0; i < 8; ++i) {
        int chunk = tid + i * 256;          // 2048 chunks of 16B per tile
        int r  = chunk >> 4;                // tile row
        int cb = (chunk & 15) * 16;         // byte col
        int sc = cb ^ ((r & 7) << 4);       // G4 XOR swizzle
        uint4 va = *(const uint4*)((const char*)ebf + ((size_t)(brow + r) << 8) + cb);
        *(uint4*)(a_tile + r * 256 + sc) = va;
        uint4 vb = *(const uint4*)((const char*)ebf + ((size_t)(bcol + r) << 8) + cb);
        *(uint4*)(b_tile + r * 256 + sc) = vb;
    }
    __syncthreads();

    const int wm = (wid >> 1) * 64, wn = (wid & 1) * 64;
    const int lhi = lane >> 4, llo = lane & 15;

    f32x4 acc[4][4];
    #pragma unroll
    for (int m = 0; m < 4; ++m)
        #pragma unroll
        for (int n = 0; n < 4; ++n)
            acc[m][n] = (f32x4){0.f, 0.f, 0.f, 0.f};

    // ---- MFMA: G = A . B^T ----
    #pragma unroll
    for (int ks = 0; ks < 4; ++ks) {
        const int cb = ks * 64 + lhi * 16;  // byte col of this lane's 8 bf16
        bf16x8 af[4], bfr[4];
        #pragma unroll
        for (int m = 0; m < 4; ++m) {
            int r = wm + m * 16 + llo;
            af[m] = *(const bf16x8*)(a_tile + r * 256 + (cb ^ ((r & 7) << 4)));
        }
        #pragma unroll
        for (int n = 0; n < 4; ++n) {
            int r = wn + n * 16 + llo;
            bfr[n] = *(const bf16x8*)(b_tile + r * 256 + (cb ^ ((r & 7) << 4)));
        }
        #pragma unroll
        for (int m = 0; m < 4; ++m)
            #pragma unroll
            for (int n = 0; n < 4; ++n)
                acc[m][n] = __builtin_amdgcn_mfma_f32_16x16x32_bf16(af[m], bfr[n], acc[m][n], 0, 0, 0);
    }

    // ---- epilogue preloads ----
    // C/D layout: col = lane&15, row = (lane>>4)*4 + reg
    const int rowbase = brow + wm;
    float sqr[4][4]; int labr[4][4]; float ser[4][4];
    #pragma unroll
    for (int m = 0; m < 4; ++m)
        #pragma unroll
        for (int r = 0; r < 4; ++r) {
            int row = rowbase + m * 16 + lhi * 4 + r;
            sqr[m][r] = sq[row];
            labr[m][r] = labels[row];
            if (PASS == 2) ser[m][r] = sum_exp[row];
        }
    float sqc[4]; int labc[4]; float sec[4];
    #pragma unroll
    for (int n = 0; n < 4; ++n) {
        int col = bcol + wn + n * 16 + llo;
        sqc[n] = sq[col];
        labc[n] = labels[col];
        if (PASS == 2) sec[n] = sum_exp[col];
    }

    if (PASS == 1) {
        float wsum[4][4] = {};
        #pragma unroll
        for (int m = 0; m < 4; ++m)
            #pragma unroll
            for (int n = 0; n < 4; ++n)
                #pragma unroll
                for (int r = 0; r < 4; ++r) {
                    float g = acc[m][n][r];
                    float d2 = fmaxf(sqr[m][r] + sqc[n] - 2.f * g, 0.f);
                    float dist = sqrtf(d2);
                    // diagonal auto-excluded: label_i == label_i
                    float w = (labr[m][r] != labc[n]) ? __expf(1.0f - dist) : 0.f;
                    wsum[m][r] += w;
                }
        // sum across the 16 llo lanes (cols) of each lane-group
        #pragma unroll
        for (int m = 0; m < 4; ++m)
            #pragma unroll
            for (int r = 0; r < 4; ++r) {
                float s = wsum[m][r];
                #pragma unroll
                for (int off = 1; off < 16; off <<= 1) s += __shfl_xor(s, off, 64);
                if (llo == 0)
                    atomicAdd(&rowsum[wm + m * 16 + lhi * 4 + r], s);  // LDS atomic
            }
        __syncthreads();
        if (tid < 128)
            partial1[(size_t)blockIdx.x * N + brow + tid] = rowsum[tid];
    } else {
        float lsum = 0.f; unsigned cnt = 0;
        #pragma unroll
        for (int m = 0; m < 4; ++m)
            #pragma unroll
            for (int n = 0; n < 4; ++n)
                #pragma unroll
                for (int r = 0; r < 4; ++r) {
                    float g = acc[m][n][r];
                    float d2 = fmaxf(sqr[m][r] + sqc[n] - 2.f * g, 0.f);
                    float dist = sqrtf(d2);
                    int row = rowbase + m * 16 + lhi * 4 + r;
                    int col = bcol + wn + n * 16 + llo;
                    bool pos = (labr[m][r] == labc[n]) && (row != col);
                    float L = __logf(ser[m][r] + sec[n]) + dist;
                    L = fmaxf(L, 0.f);
                    lsum += pos ? L * L : 0.f;
                    cnt  += pos ? 1u : 0u;
                }
        #pragma unroll
        for (int off = 1; off < 64; off <<= 1) {
            lsum += __shfl_xor(lsum, off, 64);
            cnt  += __shfl_xor(cnt, off, 64);
        }
        if (lane == 0) { bsum[wid] = (double)lsum; bcnt[wid] = cnt; }
        __syncthreads();
        if (tid == 0) {
            int bid = blockIdx.y * gridDim.x + blockIdx.x;
            partial2[bid] = bsum[0] + bsum[1] + bsum[2] + bsum[3];
            cnt2[bid] = bcnt[0] + bcnt[1] + bcnt[2] + bcnt[3];
        }
    }
}

// sum_exp[row] = sum over column-blocks of partial1[cb][row]
__global__ void reduce1_kernel(const float* __restrict__ partial1,
                               float* __restrict__ sum_exp, int N, int nCb) {
    int row = blockIdx.x * 256 + threadIdx.x;
    if (row >= N) return;
    float s = 0.f;
    for (int cb = 0; cb < nCb; ++cb) s += partial1[(size_t)cb * N + row];
    sum_exp[row] = s;
}

__global__ void finalize_kernel(const double* __restrict__ partial2,
                                const unsigned* __restrict__ cnt2,
                                int nB, float* __restrict__ out) {
    __shared__ double sds[4];
    __shared__ unsigned scn[4];
    int tid = threadIdx.x, lane = tid & 63, wid = tid >> 6;
    double t = 0.0; unsigned c = 0;
    for (int i = tid; i < nB; i += 256) { t += partial2[i]; c += cnt2[i]; }
    #pragma unroll
    for (int off = 1; off < 64; off <<= 1) {
        t += __shfl_xor(t, off, 64);
        c += __shfl_xor(c, off, 64);
    }
    if (lane == 0) { sds[wid] = t; scn[wid] = c; }
    __syncthreads();
    if (tid == 0) {
        double tt = sds[0] + sds[1] + sds[2] + sds[3];
        unsigned cc = scn[0] + scn[1] + scn[2] + scn[3];
        if (cc == 0) cc = 1;
        out[0] = (float)(tt / (double)cc * 0.5);
    }
}

extern "C" void kernel_launch(void* const* d_in, const int* in_sizes, int n_in,
                              void* d_out, int out_size, void* d_ws, size_t ws_size,
                              hipStream_t stream) {
    const float* e = (const float*)d_in[0];
    const int* labels = (const int*)d_in[1];
    const int N = in_sizes[1];                 // 8192
    const int nCb = N / 128;                   // 64
    const int nB = nCb * nCb;                  // 4096

    char* ws = (char*)d_ws;
    float*    sq       = (float*)ws;
    float*    sum_exp  = (float*)(ws + 4 * (size_t)N);
    unsigned short* ebf = (unsigned short*)(ws + 8 * (size_t)N);
    char*     p        = ws + 8 * (size_t)N + 2 * (size_t)N * 128;
    float*    partial1 = (float*)p;            // nCb * N floats
    p += (size_t)nCb * N * 4;
    p = (char*)(((size_t)p + 7) & ~(size_t)7);
    double*   partial2 = (double*)p;           // nB doubles
    p += (size_t)nB * 8;
    unsigned* cnt2     = (unsigned*)p;         // nB uints

    prep_kernel<<<N, 64, 0, stream>>>(e, sq, (unsigned*)ebf, N);
    dim3 grid(nCb, nCb);
    pass_kernel<1><<<grid, 256, 0, stream>>>(ebf, sq, labels, sum_exp,
                                             partial1, partial2, cnt2, N);
    reduce1_kernel<<<(N + 255) / 256, 256, 0, stream>>>(partial1, sum_exp, N, nCb);
    pass_kernel<2><<<grid, 256, 0, stream>>>(ebf, sq, labels, sum_exp,
                                             partial1, partial2, cnt2, N);
    finalize_kernel<<<1, 256, 0, stream>>>(partial2, cnt2, nB, (float*)d_out);
}

// Round 4
// 114.422 us; speedup vs baseline: 4.5396x; 1.5936x over previous
//
#include <hip/hip_runtime.h>
#include <hip/hip_bf16.h>

// LiftedStructureLoss on MI355X (gfx950) — symmetric upper-triangle version.
// N=8192, D=128 fp32 embeddings; int labels; scalar fp32 out.
//
// ws layout:
//   [0]          float sq[N]
//   [4N]         float sum_exp[N]
//   [8N]         bf16  ebf[N*128]        (2 MB, 256B rows)
//   [8N+2N*128]  float partial1[nCb][N]  (2 MB)
//   [...]        double partial2[nT]     (nT = nCb*(nCb+1)/2)
//   [...]        unsigned cnt2[nT]

typedef __attribute__((ext_vector_type(8))) short bf16x8;
typedef __attribute__((ext_vector_type(4))) float f32x4;

__device__ __forceinline__ unsigned short f2bf(float f) {
    unsigned u = __float_as_uint(f);
    u += 0x7fffu + ((u >> 16) & 1u);   // round-to-nearest-even
    return (unsigned short)(u >> 16);
}

// One wave per row: row sum-of-squares (fp32) + bf16 conversion.
__global__ void prep_kernel(const float* __restrict__ e, float* __restrict__ sq,
                            unsigned* __restrict__ ebf, int N) {
    int row = blockIdx.x;
    int lane = threadIdx.x;                       // 64 lanes, 2 cols each
    float2 v = ((const float2*)(e + (size_t)row * 128))[lane];
    float s = v.x * v.x + v.y * v.y;
    #pragma unroll
    for (int off = 1; off < 64; off <<= 1) s += __shfl_xor(s, off, 64);
    if (lane == 0) sq[row] = s;
    unsigned bits = (unsigned)f2bf(v.x) | ((unsigned)f2bf(v.y) << 16);
    ebf[(size_t)row * 64 + lane] = bits;
}

// Upper-triangle tile pass. PASS1: partial row+col sums of exp(1-d) over
// negatives. PASS2: partial loss + n_pos over unordered positive pairs.
// 128x128 tile, 4 waves (2x2 of 64x64). K=128 staged in 2 chunks of 64
// (single-buffered) to keep LDS at ~33KB -> 3-4 blocks/CU.
template<int PASS>
__global__ __launch_bounds__(256) void pass_kernel(
    const unsigned short* __restrict__ ebf,
    const float* __restrict__ sq,
    const int* __restrict__ labels,
    const float* __restrict__ sum_exp,   // read in PASS 2
    float* __restrict__ partial1,        // [nCb][N], written in PASS 1
    double* __restrict__ partial2,       // [nT], written in PASS 2
    unsigned* __restrict__ cnt2,         // [nT], written in PASS 2
    int N, int nCb)
{
    __shared__ __align__(16) char a_tile[128 * 128];  // one K-chunk (64 cols)
    __shared__ __align__(16) char b_tile[128 * 128];
    __shared__ float rowsum[128];
    __shared__ float colsum[128];
    __shared__ double bsum[4];
    __shared__ unsigned bcnt[4];

    const int tid = threadIdx.x;
    const int lane = tid & 63, wid = tid >> 6;

    // ---- decode linear tile id -> (bi, bj), bi <= bj ----
    const int t = blockIdx.x;
    // S(bi) = bi*(2*nCb - bi + 1)/2 ; t = S(bi) + (bj - bi)
    int bi = (int)((2.f * nCb + 1.f - __builtin_amdgcn_sqrtf(
                   (2.f * nCb + 1.f) * (2.f * nCb + 1.f) - 8.f * t)) * 0.5f);
    if (bi < 0) bi = 0;
    if (bi > nCb - 1) bi = nCb - 1;
    while (bi + 1 <= nCb - 1 && (bi + 1) * (2 * nCb - bi) / 2 <= t) ++bi;
    while (bi > 0 && bi * (2 * nCb - bi + 1) / 2 > t) --bi;
    const int bj = bi + (t - bi * (2 * nCb - bi + 1) / 2);
    const bool diag = (bi == bj);
    const int brow = bi * 128, bcol = bj * 128;

    if (tid < 128) { rowsum[tid] = 0.f; colsum[tid] = 0.f; }

    const int wm = (wid >> 1) * 64, wn = (wid & 1) * 64;
    const int lhi = lane >> 4, llo = lane & 15;

    f32x4 acc[4][4];
    #pragma unroll
    for (int m = 0; m < 4; ++m)
        #pragma unroll
        for (int n = 0; n < 4; ++n)
            acc[m][n] = (f32x4){0.f, 0.f, 0.f, 0.f};

    const char* ebfB = (const char*)ebf;

    #pragma unroll
    for (int c = 0; c < 2; ++c) {
        // ---- stage K-chunk c of both tiles, swizzled ----
        #pragma unroll
        for (int i = 0; i < 4; ++i) {
            int e2 = tid + i * 256;         // 1024 16B-entries per tile
            int r  = e2 >> 3;
            int cb = (e2 & 7) * 16;
            int sc = cb ^ ((r & 7) << 4);
            uint4 va = *(const uint4*)(ebfB + ((size_t)(brow + r) << 8) + c * 128 + cb);
            *(uint4*)(a_tile + r * 128 + sc) = va;
            uint4 vb = *(const uint4*)(ebfB + ((size_t)(bcol + r) << 8) + c * 128 + cb);
            *(uint4*)(b_tile + r * 128 + sc) = vb;
        }
        __syncthreads();

        // ---- MFMA over the 2 K=32 halves of this chunk ----
        #pragma unroll
        for (int h = 0; h < 2; ++h) {
            const int cb = h * 64 + lhi * 16;
            bf16x8 af[4], bfr[4];
            #pragma unroll
            for (int m = 0; m < 4; ++m) {
                int r = wm + m * 16 + llo;
                af[m] = *(const bf16x8*)(a_tile + r * 128 + (cb ^ ((r & 7) << 4)));
            }
            #pragma unroll
            for (int n = 0; n < 4; ++n) {
                int r = wn + n * 16 + llo;
                bfr[n] = *(const bf16x8*)(b_tile + r * 128 + (cb ^ ((r & 7) << 4)));
            }
            #pragma unroll
            for (int m = 0; m < 4; ++m)
                #pragma unroll
                for (int n = 0; n < 4; ++n)
                    acc[m][n] = __builtin_amdgcn_mfma_f32_16x16x32_bf16(af[m], bfr[n], acc[m][n], 0, 0, 0);
        }
        __syncthreads();   // all ds_reads done before restaging / epilogue LDS use
    }

    // ---- epilogue preloads ----
    // C/D layout: col = lane&15, row = (lane>>4)*4 + reg
    const int rowbase = brow + wm;
    float sqr[4][4]; int labr[4][4]; float ser[4][4];
    #pragma unroll
    for (int m = 0; m < 4; ++m)
        #pragma unroll
        for (int r = 0; r < 4; ++r) {
            int row = rowbase + m * 16 + lhi * 4 + r;
            sqr[m][r] = sq[row];
            labr[m][r] = labels[row];
            if (PASS == 2) ser[m][r] = sum_exp[row];
        }
    float sqc[4]; int labc[4]; float sec[4];
    #pragma unroll
    for (int n = 0; n < 4; ++n) {
        int col = bcol + wn + n * 16 + llo;
        sqc[n] = sq[col];
        labc[n] = labels[col];
        if (PASS == 2) sec[n] = sum_exp[col];
    }

    if (PASS == 1) {
        float wsum[4][4] = {};   // per-(m,r) row partial
        float csum[4] = {};      // per-n col partial
        #pragma unroll
        for (int m = 0; m < 4; ++m)
            #pragma unroll
            for (int n = 0; n < 4; ++n)
                #pragma unroll
                for (int r = 0; r < 4; ++r) {
                    float g = acc[m][n][r];
                    float d2 = fmaxf(sqr[m][r] + sqc[n] - 2.f * g, 0.f);
                    float dist = __builtin_amdgcn_sqrtf(d2);
                    float w = (labr[m][r] != labc[n]) ? __expf(1.0f - dist) : 0.f;
                    wsum[m][r] += w;
                    csum[n] += w;
                }
        // row sums: reduce across the 16 llo lanes
        #pragma unroll
        for (int m = 0; m < 4; ++m)
            #pragma unroll
            for (int r = 0; r < 4; ++r) {
                float s = wsum[m][r];
                #pragma unroll
                for (int off = 1; off < 16; off <<= 1) s += __shfl_xor(s, off, 64);
                if (llo == 0)
                    atomicAdd(&rowsum[wm + m * 16 + lhi * 4 + r], s);
            }
        // col sums: reduce across the 4 lhi groups
        if (!diag) {
            #pragma unroll
            for (int n = 0; n < 4; ++n) {
                float s = csum[n];
                s += __shfl_xor(s, 16, 64);
                s += __shfl_xor(s, 32, 64);
                if (lhi == 0)
                    atomicAdd(&colsum[wn + n * 16 + llo], s);
            }
        }
        __syncthreads();
        if (tid < 128) {
            partial1[(size_t)bj * N + brow + tid] = rowsum[tid];
            if (!diag)
                partial1[(size_t)bi * N + bcol + tid] = colsum[tid];
        }
    } else {
        float lsum = 0.f; unsigned cnt = 0;
        #pragma unroll
        for (int m = 0; m < 4; ++m)
            #pragma unroll
            for (int n = 0; n < 4; ++n)
                #pragma unroll
                for (int r = 0; r < 4; ++r) {
                    float g = acc[m][n][r];
                    float d2 = fmaxf(sqr[m][r] + sqc[n] - 2.f * g, 0.f);
                    float dist = __builtin_amdgcn_sqrtf(d2);
                    int lrow = wm + m * 16 + lhi * 4 + r;   // local row
                    int lcol = wn + n * 16 + llo;           // local col
                    bool pos = (labr[m][r] == labc[n]) && (!diag || lcol > lrow);
                    float L = __logf(ser[m][r] + sec[n]) + dist;
                    L = fmaxf(L, 0.f);
                    lsum += pos ? L * L : 0.f;
                    cnt  += pos ? 1u : 0u;
                }
        #pragma unroll
        for (int off = 1; off < 64; off <<= 1) {
            lsum += __shfl_xor(lsum, off, 64);
            cnt  += __shfl_xor(cnt, off, 64);
        }
        if (lane == 0) { bsum[wid] = (double)lsum; bcnt[wid] = cnt; }
        __syncthreads();
        if (tid == 0) {
            partial2[t] = bsum[0] + bsum[1] + bsum[2] + bsum[3];
            cnt2[t] = bcnt[0] + bcnt[1] + bcnt[2] + bcnt[3];
        }
    }
}

// sum_exp[row] = sum over column-blocks of partial1[cb][row]
__global__ void reduce1_kernel(const float* __restrict__ partial1,
                               float* __restrict__ sum_exp, int N, int nCb) {
    int row = blockIdx.x * 256 + threadIdx.x;
    if (row >= N) return;
    float s = 0.f;
    for (int cb = 0; cb < nCb; ++cb) s += partial1[(size_t)cb * N + row];
    sum_exp[row] = s;
}

// out = (sum over unordered pos pairs) / n_pos_unordered / 2
// (== reference's ordered_sum / n_pos_ordered / 2, both double)
__global__ void finalize_kernel(const double* __restrict__ partial2,
                                const unsigned* __restrict__ cnt2,
                                int nT, float* __restrict__ out) {
    __shared__ double sds[4];
    __shared__ unsigned scn[4];
    int tid = threadIdx.x, lane = tid & 63, wid = tid >> 6;
    double tt = 0.0; unsigned c = 0;
    for (int i = tid; i < nT; i += 256) { tt += partial2[i]; c += cnt2[i]; }
    #pragma unroll
    for (int off = 1; off < 64; off <<= 1) {
        tt += __shfl_xor(tt, off, 64);
        c  += __shfl_xor(c, off, 64);
    }
    if (lane == 0) { sds[wid] = tt; scn[wid] = c; }
    __syncthreads();
    if (tid == 0) {
        double s = sds[0] + sds[1] + sds[2] + sds[3];
        unsigned cc = scn[0] + scn[1] + scn[2] + scn[3];
        if (cc == 0) cc = 1;
        out[0] = (float)(s / (double)cc * 0.5);
    }
}

extern "C" void kernel_launch(void* const* d_in, const int* in_sizes, int n_in,
                              void* d_out, int out_size, void* d_ws, size_t ws_size,
                              hipStream_t stream) {
    const float* e = (const float*)d_in[0];
    const int* labels = (const int*)d_in[1];
    const int N = in_sizes[1];                 // 8192
    const int nCb = N / 128;                   // 64
    const int nT = nCb * (nCb + 1) / 2;        // 2080

    char* ws = (char*)d_ws;
    float*    sq       = (float*)ws;
    float*    sum_exp  = (float*)(ws + 4 * (size_t)N);
    unsigned short* ebf = (unsigned short*)(ws + 8 * (size_t)N);
    char*     p        = ws + 8 * (size_t)N + 2 * (size_t)N * 128;
    float*    partial1 = (float*)p;            // nCb * N floats
    p += (size_t)nCb * N * 4;
    p = (char*)(((size_t)p + 7) & ~(size_t)7);
    double*   partial2 = (double*)p;           // nT doubles
    p += (size_t)nT * 8;
    unsigned* cnt2     = (unsigned*)p;         // nT uints

    prep_kernel<<<N, 64, 0, stream>>>(e, sq, (unsigned*)ebf, N);
    pass_kernel<1><<<nT, 256, 0, stream>>>(ebf, sq, labels, sum_exp,
                                           partial1, partial2, cnt2, N, nCb);
    reduce1_kernel<<<(N + 255) / 256, 256, 0, stream>>>(partial1, sum_exp, N, nCb);
    pass_kernel<2><<<nT, 256, 0, stream>>>(ebf, sq, labels, sum_exp,
                                           partial1, partial2, cnt2, N, nCb);
    finalize_kernel<<<1, 256, 0, stream>>>(partial2, cnt2, nT, (float*)d_out);
}

// Round 5
// 99.740 us; speedup vs baseline: 5.2078x; 1.1472x over previous
//
#include <hip/hip_runtime.h>
#include <hip/hip_bf16.h>

// LiftedStructureLoss on MI355X (gfx950)
// N=8192, D=128 fp32 embeddings; int labels (0..99); scalar fp32 out.
//
// Structure:
//   prep:     sq[] + bf16 convert
//   hist/scan/scatter: bucket row indices by label (256 buckets)
//   pass1:    upper-triangle 128x128 tiles, full Gram, row+col sums of
//             exp(1-d) over negatives -> partial1   (512 thr, async staging)
//   reduce1:  partial1 -> sum_exp[N]
//   pass2:    per-label blocks, within-label Gram only (~1% of pairs),
//             loss + n_pos -> partial2/cnt2
//   finalize: scalar out

typedef __attribute__((ext_vector_type(8))) short bf16x8;
typedef __attribute__((ext_vector_type(4))) float f32x4;

__device__ __forceinline__ unsigned short f2bf(float f) {
    unsigned u = __float_as_uint(f);
    u += 0x7fffu + ((u >> 16) & 1u);   // round-to-nearest-even
    return (unsigned short)(u >> 16);
}

__global__ void prep_kernel(const float* __restrict__ e, float* __restrict__ sq,
                            unsigned* __restrict__ ebf, int N) {
    int row = blockIdx.x;
    int lane = threadIdx.x;                       // 64 lanes, 2 cols each
    float2 v = ((const float2*)(e + (size_t)row * 128))[lane];
    float s = v.x * v.x + v.y * v.y;
    #pragma unroll
    for (int off = 1; off < 64; off <<= 1) s += __shfl_xor(s, off, 64);
    if (lane == 0) sq[row] = s;
    unsigned bits = (unsigned)f2bf(v.x) | ((unsigned)f2bf(v.y) << 16);
    ebf[(size_t)row * 64 + lane] = bits;
}

__global__ void hist_kernel(const int* __restrict__ labels, int* __restrict__ counts, int N) {
    int i = blockIdx.x * 256 + threadIdx.x;
    if (i < N) {
        unsigned l = (unsigned)labels[i];
        if (l < 256u) atomicAdd(&counts[l], 1);
    }
}

__global__ void scan_kernel(const int* __restrict__ counts, int* __restrict__ offsets) {
    int t = threadIdx.x;               // 256
    int lane = t & 63, w = t >> 6;
    int c = counts[t];
    int v = c;
    #pragma unroll
    for (int d = 1; d < 64; d <<= 1) {
        int u = __shfl_up(v, d, 64);
        if (lane >= d) v += u;
    }
    __shared__ int wsums[4];
    if (lane == 63) wsums[w] = v;
    __syncthreads();
    int add = 0;
    for (int k = 0; k < w; ++k) add += wsums[k];
    offsets[t] = v + add - c;          // exclusive prefix
}

__global__ void scatter_kernel(const int* __restrict__ labels,
                               const int* __restrict__ offsets,
                               int* __restrict__ cursor,
                               int* __restrict__ idxbuf, int N) {
    int i = blockIdx.x * 256 + threadIdx.x;
    if (i < N) {
        unsigned l = (unsigned)labels[i];
        if (l < 256u) {
            int p = atomicAdd(&cursor[l], 1);
            idxbuf[offsets[l] + p] = i;
        }
    }
}

// PASS 1: upper-triangle tiles, 512 threads (8 waves of 64x32 output).
// Staging: global_load_lds, linear LDS dest + inverse-swizzled global src.
__global__ __launch_bounds__(512) void pass1_kernel(
    const unsigned short* __restrict__ ebf,
    const float* __restrict__ sq,
    const int* __restrict__ labels,
    float* __restrict__ partial1,      // [nCb][N]
    int N, int nCb)
{
    __shared__ __align__(16) char a_tile[128 * 128];  // one K-chunk (64 cols)
    __shared__ __align__(16) char b_tile[128 * 128];
    __shared__ float rowsum[128];
    __shared__ float colsum[128];

    const int tid = threadIdx.x;
    const int lane = tid & 63, wid = tid >> 6;

    // decode linear tile id -> (bi, bj), bi <= bj
    const int t = blockIdx.x;
    int bi = (int)((2.f * nCb + 1.f - __builtin_amdgcn_sqrtf(
                   (2.f * nCb + 1.f) * (2.f * nCb + 1.f) - 8.f * t)) * 0.5f);
    if (bi < 0) bi = 0;
    if (bi > nCb - 1) bi = nCb - 1;
    while (bi + 1 <= nCb - 1 && (bi + 1) * (2 * nCb - bi) / 2 <= t) ++bi;
    while (bi > 0 && bi * (2 * nCb - bi + 1) / 2 > t) --bi;
    const int bj = bi + (t - bi * (2 * nCb - bi + 1) / 2);
    const bool diag = (bi == bj);
    const int brow = bi * 128, bcol = bj * 128;

    if (tid < 128) { rowsum[tid] = 0.f; colsum[tid] = 0.f; }

    const int wm = (wid >> 2) * 64, wn = (wid & 3) * 32;
    const int lhi = lane >> 4, llo = lane & 15;

    f32x4 acc[4][2];
    #pragma unroll
    for (int m = 0; m < 4; ++m)
        #pragma unroll
        for (int n = 0; n < 2; ++n)
            acc[m][n] = (f32x4){0.f, 0.f, 0.f, 0.f};

    const char* ebfB = (const char*)ebf;

    #pragma unroll
    for (int c = 0; c < 2; ++c) {
        // ---- async stage: 2048 16B slots, wave wid covers [wid*256, +256) ----
        #pragma unroll
        for (int k = 0; k < 4; ++k) {
            int s = wid * 256 + k * 64;          // wave-uniform slot base
            int tsel = s >> 10;                  // 0: a_tile, 1: b_tile
            int ls = s & 1023;
            int sl = ls + lane;                  // per-lane slot within tile
            int r = sl >> 3, j = sl & 7;
            int grow = (tsel ? bcol : brow) + r;
            const void* g = ebfB + ((size_t)grow << 8) + c * 128 + ((j ^ (r & 7)) << 4);
            char* l = (tsel ? b_tile : a_tile) + ls * 16;   // wave-uniform
            __builtin_amdgcn_global_load_lds(
                (const __attribute__((address_space(1))) unsigned*)g,
                (__attribute__((address_space(3))) unsigned*)l, 16, 0, 0);
        }
        __syncthreads();   // drains vmcnt before ds_read

        #pragma unroll
        for (int h = 0; h < 2; ++h) {
            const int cb = h * 64 + lhi * 16;
            bf16x8 af[4], bfr[2];
            #pragma unroll
            for (int m = 0; m < 4; ++m) {
                int r = wm + m * 16 + llo;
                af[m] = *(const bf16x8*)(a_tile + r * 128 + (cb ^ ((r & 7) << 4)));
            }
            #pragma unroll
            for (int n = 0; n < 2; ++n) {
                int r = wn + n * 16 + llo;
                bfr[n] = *(const bf16x8*)(b_tile + r * 128 + (cb ^ ((r & 7) << 4)));
            }
            #pragma unroll
            for (int m = 0; m < 4; ++m)
                #pragma unroll
                for (int n = 0; n < 2; ++n)
                    acc[m][n] = __builtin_amdgcn_mfma_f32_16x16x32_bf16(af[m], bfr[n], acc[m][n], 0, 0, 0);
        }
        __syncthreads();
    }

    // ---- epilogue: masked exp sums ----
    const int rowbase = brow + wm;
    float sqr[4][4]; int labr[4][4];
    #pragma unroll
    for (int m = 0; m < 4; ++m)
        #pragma unroll
        for (int r = 0; r < 4; ++r) {
            int row = rowbase + m * 16 + lhi * 4 + r;
            sqr[m][r] = sq[row];
            labr[m][r] = labels[row];
        }
    float sqc[2]; int labc[2];
    #pragma unroll
    for (int n = 0; n < 2; ++n) {
        int col = bcol + wn + n * 16 + llo;
        sqc[n] = sq[col];
        labc[n] = labels[col];
    }

    float wsum[4][4] = {};
    float csum[2] = {};
    #pragma unroll
    for (int m = 0; m < 4; ++m)
        #pragma unroll
        for (int n = 0; n < 2; ++n)
            #pragma unroll
            for (int r = 0; r < 4; ++r) {
                float g = acc[m][n][r];
                float d2 = fmaxf(fmaf(-2.f, g, sqr[m][r] + sqc[n]), 0.f);
                float dist = __builtin_amdgcn_sqrtf(d2);
                float w = (labr[m][r] != labc[n]) ? __expf(1.0f - dist) : 0.f;
                wsum[m][r] += w;
                csum[n] += w;
            }
    // row sums: reduce across 16 llo lanes
    #pragma unroll
    for (int m = 0; m < 4; ++m)
        #pragma unroll
        for (int r = 0; r < 4; ++r) {
            float s = wsum[m][r];
            #pragma unroll
            for (int off = 1; off < 16; off <<= 1) s += __shfl_xor(s, off, 64);
            if (llo == 0)
                atomicAdd(&rowsum[wm + m * 16 + lhi * 4 + r], s);
        }
    // col sums: reduce across the 4 lhi groups
    if (!diag) {
        #pragma unroll
        for (int n = 0; n < 2; ++n) {
            float s = csum[n];
            s += __shfl_xor(s, 16, 64);
            s += __shfl_xor(s, 32, 64);
            if (lhi == 0)
                atomicAdd(&colsum[wn + n * 16 + llo], s);
        }
    }
    __syncthreads();
    if (tid < 128) {
        partial1[(size_t)bj * N + brow + tid] = rowsum[tid];
        if (!diag)
            partial1[(size_t)bi * N + bcol + tid] = colsum[tid];
    }
}

// sum_exp[row] = sum over column-blocks of partial1[cb][row]
__global__ void reduce1_kernel(const float* __restrict__ partial1,
                               float* __restrict__ sum_exp, int N, int nCb) {
    int row = blockIdx.x * 256 + threadIdx.x;
    if (row >= N) return;
    float s = 0.f;
    for (int cb = 0; cb < nCb; ++cb) s += partial1[(size_t)cb * N + row];
    sum_exp[row] = s;
}

// PASS 2: one block per label; within-label Gram + loss (ordered counting).
__global__ __launch_bounds__(256) void pass2_kernel(
    const unsigned short* __restrict__ ebf,
    const float* __restrict__ sq,
    const float* __restrict__ sum_exp,
    const int* __restrict__ idxbuf,
    const int* __restrict__ offsets,
    const int* __restrict__ counts,
    double* __restrict__ partial2,
    unsigned* __restrict__ cnt2)
{
    __shared__ __align__(16) char a_tile[128 * 128];
    __shared__ __align__(16) char b_tile[128 * 128];
    __shared__ double bsum[4];
    __shared__ unsigned bcnt[4];

    const int L = blockIdx.x;
    const int tid = threadIdx.x;
    const int lane = tid & 63, wid = tid >> 6;
    const int cnt = counts[L], offs = offsets[L];
    const int wm = (wid >> 1) * 64, wn = (wid & 1) * 64;
    const int lhi = lane >> 4, llo = lane & 15;
    const char* ebfB = (const char*)ebf;

    float lsum = 0.f; unsigned lcnt = 0;

    if (cnt > 1) {
        const int nSub = (cnt + 127) >> 7;
        for (int si = 0; si < nSub; ++si)
        for (int sj = si; sj < nSub; ++sj) {
            const int baseA = offs + si * 128, baseB = offs + sj * 128;
            const int cntA = min(128, cnt - si * 128);
            const int cntB = min(128, cnt - sj * 128);
            const float wgt = (si == sj) ? 1.f : 2.f;
            const unsigned wgtu = (si == sj) ? 1u : 2u;

            f32x4 acc[4][4];
            #pragma unroll
            for (int m = 0; m < 4; ++m)
                #pragma unroll
                for (int n = 0; n < 4; ++n)
                    acc[m][n] = (f32x4){0.f, 0.f, 0.f, 0.f};

            for (int c = 0; c < 2; ++c) {
                // stage 2048 slots (reg-staged gather; rows clamped, masked later)
                #pragma unroll
                for (int i2 = 0; i2 < 8; ++i2) {
                    int sl = tid + i2 * 256;
                    int tsel = sl >> 10;
                    int s = sl & 1023;
                    int r = s >> 3, j = s & 7;
                    int base = tsel ? baseB : baseA;
                    int cc = tsel ? cntB : cntA;
                    int gr = idxbuf[base + min(r, cc - 1)];
                    uint4 v = *(const uint4*)(ebfB + ((size_t)gr << 8) + c * 128 + (j << 4));
                    char* tp = tsel ? b_tile : a_tile;
                    *(uint4*)(tp + r * 128 + (((j << 4)) ^ ((r & 7) << 4))) = v;
                }
                __syncthreads();
                #pragma unroll
                for (int h = 0; h < 2; ++h) {
                    const int cb = h * 64 + lhi * 16;
                    bf16x8 af[4], bfr[4];
                    #pragma unroll
                    for (int m = 0; m < 4; ++m) {
                        int r = wm + m * 16 + llo;
                        af[m] = *(const bf16x8*)(a_tile + r * 128 + (cb ^ ((r & 7) << 4)));
                    }
                    #pragma unroll
                    for (int n = 0; n < 4; ++n) {
                        int r = wn + n * 16 + llo;
                        bfr[n] = *(const bf16x8*)(b_tile + r * 128 + (cb ^ ((r & 7) << 4)));
                    }
                    #pragma unroll
                    for (int m = 0; m < 4; ++m)
                        #pragma unroll
                        for (int n = 0; n < 4; ++n)
                            acc[m][n] = __builtin_amdgcn_mfma_f32_16x16x32_bf16(af[m], bfr[n], acc[m][n], 0, 0, 0);
                }
                __syncthreads();
            }

            // epilogue: positive-pair loss
            int giA[4][4]; float sqA[4][4], seA[4][4]; bool vA[4][4];
            #pragma unroll
            for (int m = 0; m < 4; ++m)
                #pragma unroll
                for (int r = 0; r < 4; ++r) {
                    int lr = wm + m * 16 + lhi * 4 + r;
                    vA[m][r] = lr < cntA;
                    int gi = idxbuf[baseA + min(lr, cntA - 1)];
                    giA[m][r] = gi;
                    sqA[m][r] = sq[gi];
                    seA[m][r] = sum_exp[gi];
                }
            int gjB[4]; float sqB[4], seB[4]; bool vB[4];
            #pragma unroll
            for (int n = 0; n < 4; ++n) {
                int lc = wn + n * 16 + llo;
                vB[n] = lc < cntB;
                int gj = idxbuf[baseB + min(lc, cntB - 1)];
                gjB[n] = gj;
                sqB[n] = sq[gj];
                seB[n] = sum_exp[gj];
            }
            #pragma unroll
            for (int m = 0; m < 4; ++m)
                #pragma unroll
                for (int n = 0; n < 4; ++n)
                    #pragma unroll
                    for (int r = 0; r < 4; ++r) {
                        float g = acc[m][n][r];
                        float d2 = fmaxf(fmaf(-2.f, g, sqA[m][r] + sqB[n]), 0.f);
                        float dist = __builtin_amdgcn_sqrtf(d2);
                        bool pos = vA[m][r] && vB[n] && (giA[m][r] != gjB[n]);
                        float Lv = __logf(seA[m][r] + seB[n]) + dist;
                        Lv = fmaxf(Lv, 0.f);
                        lsum += pos ? wgt * Lv * Lv : 0.f;
                        lcnt += pos ? wgtu : 0u;
                    }
        }
    }

    // block reduce
    #pragma unroll
    for (int off = 1; off < 64; off <<= 1) {
        lsum += __shfl_xor(lsum, off, 64);
        lcnt += __shfl_xor(lcnt, off, 64);
    }
    if (lane == 0) { bsum[wid] = (double)lsum; bcnt[wid] = lcnt; }
    __syncthreads();
    if (tid == 0) {
        partial2[L] = bsum[0] + bsum[1] + bsum[2] + bsum[3];
        cnt2[L] = bcnt[0] + bcnt[1] + bcnt[2] + bcnt[3];
    }
}

// out = ordered_sum / n_pos_ordered / 2
__global__ void finalize_kernel(const double* __restrict__ partial2,
                                const unsigned* __restrict__ cnt2,
                                int nT, float* __restrict__ out) {
    __shared__ double sds[4];
    __shared__ unsigned scn[4];
    int tid = threadIdx.x, lane = tid & 63, wid = tid >> 6;
    double tt = 0.0; unsigned c = 0;
    for (int i = tid; i < nT; i += 256) { tt += partial2[i]; c += cnt2[i]; }
    #pragma unroll
    for (int off = 1; off < 64; off <<= 1) {
        tt += __shfl_xor(tt, off, 64);
        c  += __shfl_xor(c, off, 64);
    }
    if (lane == 0) { sds[wid] = tt; scn[wid] = c; }
    __syncthreads();
    if (tid == 0) {
        double s = sds[0] + sds[1] + sds[2] + sds[3];
        unsigned cc = scn[0] + scn[1] + scn[2] + scn[3];
        if (cc == 0) cc = 1;
        out[0] = (float)(s / (double)cc * 0.5);
    }
}

extern "C" void kernel_launch(void* const* d_in, const int* in_sizes, int n_in,
                              void* d_out, int out_size, void* d_ws, size_t ws_size,
                              hipStream_t stream) {
    const float* e = (const float*)d_in[0];
    const int* labels = (const int*)d_in[1];
    const int N = in_sizes[1];                 // 8192
    const int nCb = N / 128;                   // 64
    const int nT = nCb * (nCb + 1) / 2;        // 2080
    const int NL = 256;

    char* ws = (char*)d_ws;
    float*    sq       = (float*)ws;
    float*    sum_exp  = (float*)(ws + 4 * (size_t)N);
    unsigned short* ebf = (unsigned short*)(ws + 8 * (size_t)N);
    char*     p        = ws + 8 * (size_t)N + 256 * (size_t)N;
    float*    partial1 = (float*)p;            // nCb*N floats (2 MB)
    p += (size_t)nCb * N * 4;
    int*      counts   = (int*)p;      p += NL * 4;
    int*      cursor   = (int*)p;      p += NL * 4;
    int*      offsets  = (int*)p;      p += NL * 4;
    p = (char*)(((size_t)p + 7) & ~(size_t)7);
    double*   partial2 = (double*)p;   p += NL * 8;
    unsigned* cnt2     = (unsigned*)p; p += NL * 4;
    int*      idxbuf   = (int*)p;

    (void)hipMemsetAsync(counts, 0, 2 * NL * sizeof(int), stream);  // counts+cursor
    prep_kernel<<<N, 64, 0, stream>>>(e, sq, (unsigned*)ebf, N);
    hist_kernel<<<(N + 255) / 256, 256, 0, stream>>>(labels, counts, N);
    scan_kernel<<<1, 256, 0, stream>>>(counts, offsets);
    scatter_kernel<<<(N + 255) / 256, 256, 0, stream>>>(labels, offsets, cursor, idxbuf, N);
    pass1_kernel<<<nT, 512, 0, stream>>>(ebf, sq, labels, partial1, N, nCb);
    reduce1_kernel<<<(N + 255) / 256, 256, 0, stream>>>(partial1, sum_exp, N, nCb);
    pass2_kernel<<<NL, 256, 0, stream>>>(ebf, sq, sum_exp, idxbuf, offsets, counts,
                                         partial2, cnt2);
    finalize_kernel<<<1, 256, 0, stream>>>(partial2, cnt2, NL, (float*)d_out);
}

// Round 6
// 81.618 us; speedup vs baseline: 6.3642x; 1.2220x over previous
//
#include <hip/hip_runtime.h>
#include <hip/hip_bf16.h>

// LiftedStructureLoss on MI355X (gfx950)
// N=8192, D=128 fp32 embeddings; int labels (0..99); scalar fp32 out.
//
// Structure:
//   prep:     sq[] + bf16 convert
//   bucket:   single-block zero+hist+scan+scatter (labels -> idxbuf)
//   pass1:    upper-triangle 128x128 tiles, full Gram, row+col sums of
//             exp(1-d) over negatives -> partial1   (512 thr, async staging)
//   reduce1:  partial1 -> sum_exp[N]
//   pass2:    per-label blocks, within-label Gram only (~1% of pairs),
//             loss + n_pos -> partial2/cnt2
//   finalize: scalar out

typedef __attribute__((ext_vector_type(8))) short bf16x8;
typedef __attribute__((ext_vector_type(4))) float f32x4;

__device__ __forceinline__ unsigned short f2bf(float f) {
    unsigned u = __float_as_uint(f);
    u += 0x7fffu + ((u >> 16) & 1u);   // round-to-nearest-even
    return (unsigned short)(u >> 16);
}

__global__ void prep_kernel(const float* __restrict__ e, float* __restrict__ sq,
                            unsigned* __restrict__ ebf, int N) {
    int row = blockIdx.x;
    int lane = threadIdx.x;                       // 64 lanes, 2 cols each
    float2 v = ((const float2*)(e + (size_t)row * 128))[lane];
    float s = v.x * v.x + v.y * v.y;
    #pragma unroll
    for (int off = 1; off < 64; off <<= 1) s += __shfl_xor(s, off, 64);
    if (lane == 0) sq[row] = s;
    unsigned bits = (unsigned)f2bf(v.x) | ((unsigned)f2bf(v.y) << 16);
    ebf[(size_t)row * 64 + lane] = bits;
}

// Single block: zero + histogram + exclusive scan + scatter. Replaces
// hipMemsetAsync + 3 kernels (the runtime fill kernel cost 40us/replay).
__global__ __launch_bounds__(1024) void bucket_kernel(
    const int* __restrict__ labels,
    int* __restrict__ counts_out,    // [256]
    int* __restrict__ offsets_out,   // [256]
    int* __restrict__ idxbuf,        // [N]
    int N)
{
    __shared__ int cnt[256];
    __shared__ int off[256];
    const int tid = threadIdx.x;
    if (tid < 256) cnt[tid] = 0;
    __syncthreads();
    for (int i = tid; i < N; i += 1024)
        atomicAdd(&cnt[(unsigned)labels[i] & 255u], 1);
    __syncthreads();
    if (tid < 64) {
        int base = tid * 4;
        int c0 = cnt[base], c1 = cnt[base + 1], c2 = cnt[base + 2], c3 = cnt[base + 3];
        int s = c0 + c1 + c2 + c3;
        int v = s;
        #pragma unroll
        for (int d = 1; d < 64; d <<= 1) {
            int u = __shfl_up(v, d, 64);
            if (tid >= d) v += u;
        }
        int excl = v - s;
        off[base]     = excl;
        off[base + 1] = excl + c0;
        off[base + 2] = excl + c0 + c1;
        off[base + 3] = excl + c0 + c1 + c2;
    }
    __syncthreads();
    if (tid < 256) cnt[tid] = off[tid];   // reuse cnt as cursor
    __syncthreads();
    for (int i = tid; i < N; i += 1024) {
        int l = (unsigned)labels[i] & 255u;
        int p = atomicAdd(&cnt[l], 1);
        idxbuf[p] = i;
    }
    __syncthreads();
    if (tid < 256) {
        offsets_out[tid] = off[tid];
        counts_out[tid] = cnt[tid] - off[tid];
    }
}

// PASS 1: upper-triangle tiles, 512 threads (8 waves of 64x32 output).
// Staging: global_load_lds, linear LDS dest + inverse-swizzled global src.
__global__ __launch_bounds__(512) void pass1_kernel(
    const unsigned short* __restrict__ ebf,
    const float* __restrict__ sq,
    const int* __restrict__ labels,
    float* __restrict__ partial1,      // [nCb][N]
    int N, int nCb)
{
    __shared__ __align__(16) char a_tile[128 * 128];  // one K-chunk (64 cols)
    __shared__ __align__(16) char b_tile[128 * 128];
    __shared__ float rowsum[128];
    __shared__ float colsum[128];

    const int tid = threadIdx.x;
    const int lane = tid & 63, wid = tid >> 6;

    // decode linear tile id -> (bi, bj), bi <= bj
    const int t = blockIdx.x;
    int bi = (int)((2.f * nCb + 1.f - __builtin_amdgcn_sqrtf(
                   (2.f * nCb + 1.f) * (2.f * nCb + 1.f) - 8.f * t)) * 0.5f);
    if (bi < 0) bi = 0;
    if (bi > nCb - 1) bi = nCb - 1;
    while (bi + 1 <= nCb - 1 && (bi + 1) * (2 * nCb - bi) / 2 <= t) ++bi;
    while (bi > 0 && bi * (2 * nCb - bi + 1) / 2 > t) --bi;
    const int bj = bi + (t - bi * (2 * nCb - bi + 1) / 2);
    const bool diag = (bi == bj);
    const int brow = bi * 128, bcol = bj * 128;

    if (tid < 128) { rowsum[tid] = 0.f; colsum[tid] = 0.f; }

    const int wm = (wid >> 2) * 64, wn = (wid & 3) * 32;
    const int lhi = lane >> 4, llo = lane & 15;

    f32x4 acc[4][2];
    #pragma unroll
    for (int m = 0; m < 4; ++m)
        #pragma unroll
        for (int n = 0; n < 2; ++n)
            acc[m][n] = (f32x4){0.f, 0.f, 0.f, 0.f};

    const char* ebfB = (const char*)ebf;

    #pragma unroll
    for (int c = 0; c < 2; ++c) {
        // ---- async stage: 2048 16B slots, wave wid covers [wid*256, +256) ----
        #pragma unroll
        for (int k = 0; k < 4; ++k) {
            int s = wid * 256 + k * 64;          // wave-uniform slot base
            int tsel = s >> 10;                  // 0: a_tile, 1: b_tile
            int ls = s & 1023;
            int sl = ls + lane;                  // per-lane slot within tile
            int r = sl >> 3, j = sl & 7;
            int grow = (tsel ? bcol : brow) + r;
            const void* g = ebfB + ((size_t)grow << 8) + c * 128 + ((j ^ (r & 7)) << 4);
            char* l = (tsel ? b_tile : a_tile) + ls * 16;   // wave-uniform
            __builtin_amdgcn_global_load_lds(
                (const __attribute__((address_space(1))) unsigned*)g,
                (__attribute__((address_space(3))) unsigned*)l, 16, 0, 0);
        }
        __syncthreads();   // drains vmcnt before ds_read

        #pragma unroll
        for (int h = 0; h < 2; ++h) {
            const int cb = h * 64 + lhi * 16;
            bf16x8 af[4], bfr[2];
            #pragma unroll
            for (int m = 0; m < 4; ++m) {
                int r = wm + m * 16 + llo;
                af[m] = *(const bf16x8*)(a_tile + r * 128 + (cb ^ ((r & 7) << 4)));
            }
            #pragma unroll
            for (int n = 0; n < 2; ++n) {
                int r = wn + n * 16 + llo;
                bfr[n] = *(const bf16x8*)(b_tile + r * 128 + (cb ^ ((r & 7) << 4)));
            }
            #pragma unroll
            for (int m = 0; m < 4; ++m)
                #pragma unroll
                for (int n = 0; n < 2; ++n)
                    acc[m][n] = __builtin_amdgcn_mfma_f32_16x16x32_bf16(af[m], bfr[n], acc[m][n], 0, 0, 0);
        }
        __syncthreads();
    }

    // ---- epilogue: masked exp sums ----
    const int rowbase = brow + wm;
    float sqr[4][4]; int labr[4][4];
    #pragma unroll
    for (int m = 0; m < 4; ++m)
        #pragma unroll
        for (int r = 0; r < 4; ++r) {
            int row = rowbase + m * 16 + lhi * 4 + r;
            sqr[m][r] = sq[row];
            labr[m][r] = labels[row];
        }
    float sqc[2]; int labc[2];
    #pragma unroll
    for (int n = 0; n < 2; ++n) {
        int col = bcol + wn + n * 16 + llo;
        sqc[n] = sq[col];
        labc[n] = labels[col];
    }

    float wsum[4][4] = {};
    float csum[2] = {};
    #pragma unroll
    for (int m = 0; m < 4; ++m)
        #pragma unroll
        for (int n = 0; n < 2; ++n)
            #pragma unroll
            for (int r = 0; r < 4; ++r) {
                float g = acc[m][n][r];
                float d2 = fmaxf(fmaf(-2.f, g, sqr[m][r] + sqc[n]), 0.f);
                float dist = __builtin_amdgcn_sqrtf(d2);
                float w = (labr[m][r] != labc[n]) ? __expf(1.0f - dist) : 0.f;
                wsum[m][r] += w;
                csum[n] += w;
            }
    // row sums: reduce across 16 llo lanes
    #pragma unroll
    for (int m = 0; m < 4; ++m)
        #pragma unroll
        for (int r = 0; r < 4; ++r) {
            float s = wsum[m][r];
            #pragma unroll
            for (int off = 1; off < 16; off <<= 1) s += __shfl_xor(s, off, 64);
            if (llo == 0)
                atomicAdd(&rowsum[wm + m * 16 + lhi * 4 + r], s);
        }
    // col sums: reduce across the 4 lhi groups
    if (!diag) {
        #pragma unroll
        for (int n = 0; n < 2; ++n) {
            float s = csum[n];
            s += __shfl_xor(s, 16, 64);
            s += __shfl_xor(s, 32, 64);
            if (lhi == 0)
                atomicAdd(&colsum[wn + n * 16 + llo], s);
        }
    }
    __syncthreads();
    if (tid < 128) {
        partial1[(size_t)bj * N + brow + tid] = rowsum[tid];
        if (!diag)
            partial1[(size_t)bi * N + bcol + tid] = colsum[tid];
    }
}

// sum_exp[row] = sum over column-blocks of partial1[cb][row]
__global__ void reduce1_kernel(const float* __restrict__ partial1,
                               float* __restrict__ sum_exp, int N, int nCb) {
    int row = blockIdx.x * 256 + threadIdx.x;
    if (row >= N) return;
    float s = 0.f;
    for (int cb = 0; cb < nCb; ++cb) s += partial1[(size_t)cb * N + row];
    sum_exp[row] = s;
}

// PASS 2: one block per label; within-label Gram + loss (ordered counting).
__global__ __launch_bounds__(256) void pass2_kernel(
    const unsigned short* __restrict__ ebf,
    const float* __restrict__ sq,
    const float* __restrict__ sum_exp,
    const int* __restrict__ idxbuf,
    const int* __restrict__ offsets,
    const int* __restrict__ counts,
    double* __restrict__ partial2,
    unsigned* __restrict__ cnt2)
{
    __shared__ __align__(16) char a_tile[128 * 128];
    __shared__ __align__(16) char b_tile[128 * 128];
    __shared__ double bsum[4];
    __shared__ unsigned bcnt[4];

    const int L = blockIdx.x;
    const int tid = threadIdx.x;
    const int lane = tid & 63, wid = tid >> 6;
    const int cnt = counts[L], offs = offsets[L];
    const int wm = (wid >> 1) * 64, wn = (wid & 1) * 64;
    const int lhi = lane >> 4, llo = lane & 15;
    const char* ebfB = (const char*)ebf;

    float lsum = 0.f; unsigned lcnt = 0;

    if (cnt > 1) {
        const int nSub = (cnt + 127) >> 7;
        for (int si = 0; si < nSub; ++si)
        for (int sj = si; sj < nSub; ++sj) {
            const int baseA = offs + si * 128, baseB = offs + sj * 128;
            const int cntA = min(128, cnt - si * 128);
            const int cntB = min(128, cnt - sj * 128);
            const float wgt = (si == sj) ? 1.f : 2.f;
            const unsigned wgtu = (si == sj) ? 1u : 2u;

            f32x4 acc[4][4];
            #pragma unroll
            for (int m = 0; m < 4; ++m)
                #pragma unroll
                for (int n = 0; n < 4; ++n)
                    acc[m][n] = (f32x4){0.f, 0.f, 0.f, 0.f};

            for (int c = 0; c < 2; ++c) {
                // stage 2048 slots (reg-staged gather; rows clamped, masked later)
                #pragma unroll
                for (int i2 = 0; i2 < 8; ++i2) {
                    int sl = tid + i2 * 256;
                    int tsel = sl >> 10;
                    int s = sl & 1023;
                    int r = s >> 3, j = s & 7;
                    int base = tsel ? baseB : baseA;
                    int cc = tsel ? cntB : cntA;
                    int gr = idxbuf[base + min(r, cc - 1)];
                    uint4 v = *(const uint4*)(ebfB + ((size_t)gr << 8) + c * 128 + (j << 4));
                    char* tp = tsel ? b_tile : a_tile;
                    *(uint4*)(tp + r * 128 + (((j << 4)) ^ ((r & 7) << 4))) = v;
                }
                __syncthreads();
                #pragma unroll
                for (int h = 0; h < 2; ++h) {
                    const int cb = h * 64 + lhi * 16;
                    bf16x8 af[4], bfr[4];
                    #pragma unroll
                    for (int m = 0; m < 4; ++m) {
                        int r = wm + m * 16 + llo;
                        af[m] = *(const bf16x8*)(a_tile + r * 128 + (cb ^ ((r & 7) << 4)));
                    }
                    #pragma unroll
                    for (int n = 0; n < 4; ++n) {
                        int r = wn + n * 16 + llo;
                        bfr[n] = *(const bf16x8*)(b_tile + r * 128 + (cb ^ ((r & 7) << 4)));
                    }
                    #pragma unroll
                    for (int m = 0; m < 4; ++m)
                        #pragma unroll
                        for (int n = 0; n < 4; ++n)
                            acc[m][n] = __builtin_amdgcn_mfma_f32_16x16x32_bf16(af[m], bfr[n], acc[m][n], 0, 0, 0);
                }
                __syncthreads();
            }

            // epilogue: positive-pair loss
            int giA[4][4]; float sqA[4][4], seA[4][4]; bool vA[4][4];
            #pragma unroll
            for (int m = 0; m < 4; ++m)
                #pragma unroll
                for (int r = 0; r < 4; ++r) {
                    int lr = wm + m * 16 + lhi * 4 + r;
                    vA[m][r] = lr < cntA;
                    int gi = idxbuf[baseA + min(lr, cntA - 1)];
                    giA[m][r] = gi;
                    sqA[m][r] = sq[gi];
                    seA[m][r] = sum_exp[gi];
                }
            int gjB[4]; float sqB[4], seB[4]; bool vB[4];
            #pragma unroll
            for (int n = 0; n < 4; ++n) {
                int lc = wn + n * 16 + llo;
                vB[n] = lc < cntB;
                int gj = idxbuf[baseB + min(lc, cntB - 1)];
                gjB[n] = gj;
                sqB[n] = sq[gj];
                seB[n] = sum_exp[gj];
            }
            #pragma unroll
            for (int m = 0; m < 4; ++m)
                #pragma unroll
                for (int n = 0; n < 4; ++n)
                    #pragma unroll
                    for (int r = 0; r < 4; ++r) {
                        float g = acc[m][n][r];
                        float d2 = fmaxf(fmaf(-2.f, g, sqA[m][r] + sqB[n]), 0.f);
                        float dist = __builtin_amdgcn_sqrtf(d2);
                        bool pos = vA[m][r] && vB[n] && (giA[m][r] != gjB[n]);
                        float Lv = __logf(seA[m][r] + seB[n]) + dist;
                        Lv = fmaxf(Lv, 0.f);
                        lsum += pos ? wgt * Lv * Lv : 0.f;
                        lcnt += pos ? wgtu : 0u;
                    }
        }
    }

    // block reduce
    #pragma unroll
    for (int off = 1; off < 64; off <<= 1) {
        lsum += __shfl_xor(lsum, off, 64);
        lcnt += __shfl_xor(lcnt, off, 64);
    }
    if (lane == 0) { bsum[wid] = (double)lsum; bcnt[wid] = lcnt; }
    __syncthreads();
    if (tid == 0) {
        partial2[L] = bsum[0] + bsum[1] + bsum[2] + bsum[3];
        cnt2[L] = bcnt[0] + bcnt[1] + bcnt[2] + bcnt[3];
    }
}

// out = ordered_sum / n_pos_ordered / 2
__global__ void finalize_kernel(const double* __restrict__ partial2,
                                const unsigned* __restrict__ cnt2,
                                int nT, float* __restrict__ out) {
    __shared__ double sds[4];
    __shared__ unsigned scn[4];
    int tid = threadIdx.x, lane = tid & 63, wid = tid >> 6;
    double tt = 0.0; unsigned c = 0;
    for (int i = tid; i < nT; i += 256) { tt += partial2[i]; c += cnt2[i]; }
    #pragma unroll
    for (int off = 1; off < 64; off <<= 1) {
        tt += __shfl_xor(tt, off, 64);
        c  += __shfl_xor(c, off, 64);
    }
    if (lane == 0) { sds[wid] = tt; scn[wid] = c; }
    __syncthreads();
    if (tid == 0) {
        double s = sds[0] + sds[1] + sds[2] + sds[3];
        unsigned cc = scn[0] + scn[1] + scn[2] + scn[3];
        if (cc == 0) cc = 1;
        out[0] = (float)(s / (double)cc * 0.5);
    }
}

extern "C" void kernel_launch(void* const* d_in, const int* in_sizes, int n_in,
                              void* d_out, int out_size, void* d_ws, size_t ws_size,
                              hipStream_t stream) {
    const float* e = (const float*)d_in[0];
    const int* labels = (const int*)d_in[1];
    const int N = in_sizes[1];                 // 8192
    const int nCb = N / 128;                   // 64
    const int nT = nCb * (nCb + 1) / 2;        // 2080
    const int NL = 256;

    char* ws = (char*)d_ws;
    float*    sq       = (float*)ws;
    float*    sum_exp  = (float*)(ws + 4 * (size_t)N);
    unsigned short* ebf = (unsigned short*)(ws + 8 * (size_t)N);
    char*     p        = ws + 8 * (size_t)N + 256 * (size_t)N;
    float*    partial1 = (float*)p;            // nCb*N floats (2 MB)
    p += (size_t)nCb * N * 4;
    int*      counts   = (int*)p;      p += NL * 4;
    int*      offsets  = (int*)p;      p += NL * 4;
    p = (char*)(((size_t)p + 7) & ~(size_t)7);
    double*   partial2 = (double*)p;   p += NL * 8;
    unsigned* cnt2     = (unsigned*)p; p += NL * 4;
    int*      idxbuf   = (int*)p;

    prep_kernel<<<N, 64, 0, stream>>>(e, sq, (unsigned*)ebf, N);
    bucket_kernel<<<1, 1024, 0, stream>>>(labels, counts, offsets, idxbuf, N);
    pass1_kernel<<<nT, 512, 0, stream>>>(ebf, sq, labels, partial1, N, nCb);
    reduce1_kernel<<<(N + 255) / 256, 256, 0, stream>>>(partial1, sum_exp, N, nCb);
    pass2_kernel<<<NL, 256, 0, stream>>>(ebf, sq, sum_exp, idxbuf, offsets, counts,
                                         partial2, cnt2);
    finalize_kernel<<<1, 256, 0, stream>>>(partial2, cnt2, NL, (float*)d_out);
}